// Round 11
// baseline (828.961 us; speedup 1.0000x reference)
//
#include <hip/hip_runtime.h>
#include <hip/hip_bf16.h>
#include <math.h>

// ---------------------------------------------------------------------------
// Model constants
// ---------------------------------------------------------------------------
#define NBATCH 5
#define SEQ    1024
#define T      1025          // SEQ + 1 (cls token)
#define ROWS   (NBATCH * T)  // 5125
#define MP     5248          // ROWS padded to 41*128 for MFMA tiles
#define DM     512
#define DFF    2048
#define NHEAD  8
#define HD     64
#define NTOK   51
#define MLPDIM 256
#define NCLS   7
#define GH     3
#define GHID   64
#define GCLS   5
#define NGRAPH (SEQ * 5)     // 5120
#define QKVN   1536          // fused QKV output width
#define TPAD   1152          // T padded to 9*128 for V^T buffer

typedef __attribute__((ext_vector_type(8))) short bf16x8;
typedef __attribute__((ext_vector_type(4))) float f32x4;

#define GM_AS(p)  ((const __attribute__((address_space(1))) void*)(p))
#define LDS_AS(p) ((__attribute__((address_space(3))) void*)(p))

__device__ __forceinline__ unsigned short f2bf(float f) {
    unsigned int u = __float_as_uint(f);
    unsigned int r = (u + 0x7FFFu + ((u >> 16) & 1u)) >> 16;
    return (unsigned short)r;
}
__device__ __forceinline__ float bf2f(unsigned short u) {
    return __uint_as_float((unsigned int)u << 16);
}

// ---------------------------------------------------------------------------
// Mega-setup: all weight transposes (fp32->bf16, [K][N]->[N][K]) + bias concat.
// ---------------------------------------------------------------------------
__global__ __launch_bounds__(256) void setup_kernel(
    const float* __restrict__ Wq, const float* __restrict__ Wk,
    const float* __restrict__ Wv, const float* __restrict__ Wo_,
    const float* __restrict__ W1, const float* __restrict__ W2,
    const float* __restrict__ bq, const float* __restrict__ bk,
    const float* __restrict__ bv,
    unsigned short* __restrict__ Wqkvt, unsigned short* __restrict__ Wot,
    unsigned short* __restrict__ W1t, unsigned short* __restrict__ W2t,
    float* __restrict__ bqkv)
{
    int id = blockIdx.x;
    if (id >= 12288) {              // bias concat: 4 blocks, one per layer
        int i = id - 12288;
        #pragma unroll
        for (int rep = 0; rep < 2; ++rep) {
            int t = threadIdx.x + rep * 256;
            bqkv[i * QKVN + t]        = bq[i * DM + t];
            bqkv[i * QKVN + 512 + t]  = bk[i * DM + t];
            bqkv[i * QKVN + 1024 + t] = bv[i * DM + t];
        }
        return;
    }
    const float* W; unsigned short* Wt; int K, N, z, bx, by; long dstride;
    if (id < 4096) {                // Wq/Wk/Wv/Wo: 512x512
        int g = id >> 10, lid = id & 1023;
        K = DM; N = DM;
        z = lid >> 8; int r2 = lid & 255; by = r2 >> 4; bx = r2 & 15;
        if (g < 3) { W = (g == 0) ? Wq : (g == 1) ? Wk : Wv;
                     Wt = Wqkvt + (size_t)g * DM * DM; dstride = (long)QKVN * DM; }
        else       { W = Wo_; Wt = Wot; dstride = (long)DM * DM; }
    } else if (id < 8192) {         // W1: K=512, N=2048
        int lid = id - 4096;
        K = DM; N = DFF;
        z = lid >> 10; int r2 = lid & 1023; by = r2 >> 6; bx = r2 & 63;
        W = W1; Wt = W1t; dstride = (long)DM * DFF;
    } else {                        // W2: K=2048, N=512
        int lid = id - 8192;
        K = DFF; N = DM;
        z = lid >> 10; int r2 = lid & 1023; by = r2 >> 4; bx = r2 & 15;
        W = W2; Wt = W2t; dstride = (long)DFF * DM;
    }
    const float* Wm = W + (size_t)z * K * N;
    unsigned short* Wo2 = Wt + (size_t)z * dstride;
    __shared__ float tile[32][33];
    int bX = bx * 32, bY = by * 32;
    int tx = threadIdx.x & 31, ty = threadIdx.x >> 5;
    #pragma unroll
    for (int i = 0; i < 32; i += 8)
        tile[ty + i][tx] = Wm[(size_t)(bY + ty + i) * N + bX + tx];
    __syncthreads();
    #pragma unroll
    for (int i = 0; i < 32; i += 8)
        Wo2[(size_t)(bX + ty + i) * K + bY + tx] = f2bf(tile[tx][ty + i]);
}

// ---------------------------------------------------------------------------
// bf16 MFMA GEMM: C[M][N] = A[M][K] @ Bt[N][K]^T + bias. 128x128 tile, BK=64.
// If vt != null, blocks covering cols >= 1024 (the V part of the QKV output)
// also scatter the transposed V into vt[(bh*64+d)][TPAD] (fused vtrans).
// ---------------------------------------------------------------------------
__global__ __launch_bounds__(256) void gemm_mfma(
    const unsigned short* __restrict__ A, const unsigned short* __restrict__ Bt,
    const float* __restrict__ bias, float* __restrict__ Cf,
    unsigned short* __restrict__ Cb, unsigned short* __restrict__ vt,
    int N, int K, int relu)
{
    __shared__ unsigned short As[128 * 64];
    __shared__ unsigned short Bs[128 * 64];
    int tid = threadIdx.x;
    int l = tid & 63, w = tid >> 6;
    int wr = w & 1, wc = w >> 1;
    int mlane = l & 15, quad = l >> 4;
    int m0 = blockIdx.y * 128, n0 = blockIdx.x * 128;

    f32x4 acc[4][4] = {};

    for (int k0 = 0; k0 < K; k0 += 64) {
        __syncthreads();
        #pragma unroll
        for (int it = 0; it < 4; ++it) {
            int c = tid + it * 256;
            int row = c >> 3, cc = c & 7;
            const unsigned short* ga = A  + (size_t)(m0 + row) * K + k0 + cc * 8;
            __builtin_amdgcn_global_load_lds(GM_AS(ga), LDS_AS(As + c * 8), 16, 0, 0);
            const unsigned short* gb = Bt + (size_t)(n0 + row) * K + k0 + cc * 8;
            __builtin_amdgcn_global_load_lds(GM_AS(gb), LDS_AS(Bs + c * 8), 16, 0, 0);
        }
        __syncthreads();
        #pragma unroll
        for (int half = 0; half < 2; ++half) {
            int ko = half * 32 + quad * 8;
            bf16x8 afrag[4], bfrag[4];
            #pragma unroll
            for (int mi = 0; mi < 4; ++mi)
                afrag[mi] = *(const bf16x8*)(As + (wr * 64 + mi * 16 + mlane) * 64 + ko);
            #pragma unroll
            for (int ni = 0; ni < 4; ++ni)
                bfrag[ni] = *(const bf16x8*)(Bs + (wc * 64 + ni * 16 + mlane) * 64 + ko);
            #pragma unroll
            for (int mi = 0; mi < 4; ++mi)
                #pragma unroll
                for (int ni = 0; ni < 4; ++ni)
                    acc[mi][ni] = __builtin_amdgcn_mfma_f32_16x16x32_bf16(
                        afrag[mi], bfrag[ni], acc[mi][ni], 0, 0, 0);
        }
    }

    #pragma unroll
    for (int mi = 0; mi < 4; ++mi) {
        #pragma unroll
        for (int r = 0; r < 4; ++r) {
            int gm = m0 + wr * 64 + mi * 16 + quad * 4 + r;
            size_t rowoff = (size_t)gm * N;
            #pragma unroll
            for (int ni = 0; ni < 4; ++ni) {
                int gn = n0 + wc * 64 + ni * 16 + mlane;
                float val = acc[mi][ni][r] + bias[gn];
                if (relu) val = fmaxf(val, 0.f);
                if (Cb) Cb[rowoff + gn] = f2bf(val);
                else    Cf[rowoff + gn] = val;
            }
        }
    }

    // fused V^T scatter (QKV gemm only; V columns live at gn >= 1024)
    if (vt && n0 + wc * 64 >= 1024) {
        #pragma unroll
        for (int mi = 0; mi < 4; ++mi) {
            int gm0 = m0 + wr * 64 + mi * 16 + quad * 4;
            if (gm0 >= ROWS) continue;
            int b = gm0 / T;
            int t = gm0 - b * T;
            bool pack = (t + 3 < T) && (gm0 + 3 < ROWS);
            #pragma unroll
            for (int ni = 0; ni < 4; ++ni) {
                int gn = n0 + wc * 64 + ni * 16 + mlane;
                int hd = gn - 1024;
                float bs = bias[gn];
                if (pack) {
                    int bh = b * 8 + (hd >> 6), d = hd & 63;
                    ushort4 pk;
                    pk.x = f2bf(acc[mi][ni][0] + bs);
                    pk.y = f2bf(acc[mi][ni][1] + bs);
                    pk.z = f2bf(acc[mi][ni][2] + bs);
                    pk.w = f2bf(acc[mi][ni][3] + bs);
                    *(ushort4*)(vt + (size_t)(bh * 64 + d) * TPAD + t) = pk;
                } else {
                    #pragma unroll
                    for (int r = 0; r < 4; ++r) {
                        int gmr = gm0 + r;
                        if (gmr >= ROWS) continue;
                        int br = gmr / T, tr = gmr - br * T;
                        int bh = br * 8 + (hd >> 6), d = hd & 63;
                        vt[(size_t)(bh * 64 + d) * TPAD + tr] = f2bf(acc[mi][ni][r] + bs);
                    }
                }
            }
        }
    }
}

// ---------------------------------------------------------------------------
// Split-K bf16 MFMA GEMM: writes bf16 partials; combined in add_lnp.
// ---------------------------------------------------------------------------
__global__ __launch_bounds__(256) void gemm_mfma_sk(
    const unsigned short* __restrict__ A, const unsigned short* __restrict__ Bt,
    unsigned short* __restrict__ part, int N, int K)
{
    __shared__ unsigned short As[128 * 64];
    __shared__ unsigned short Bs[128 * 64];
    int tid = threadIdx.x;
    int l = tid & 63, w = tid >> 6;
    int wr = w & 1, wc = w >> 1;
    int mlane = l & 15, quad = l >> 4;
    int m0 = blockIdx.y * 128, n0 = blockIdx.x * 128;
    int kper = K / gridDim.z;
    int kbeg = blockIdx.z * kper;

    f32x4 acc[4][4] = {};

    for (int k0 = kbeg; k0 < kbeg + kper; k0 += 64) {
        __syncthreads();
        #pragma unroll
        for (int it = 0; it < 4; ++it) {
            int c = tid + it * 256;
            int row = c >> 3, cc = c & 7;
            const unsigned short* ga = A  + (size_t)(m0 + row) * K + k0 + cc * 8;
            __builtin_amdgcn_global_load_lds(GM_AS(ga), LDS_AS(As + c * 8), 16, 0, 0);
            const unsigned short* gb = Bt + (size_t)(n0 + row) * K + k0 + cc * 8;
            __builtin_amdgcn_global_load_lds(GM_AS(gb), LDS_AS(Bs + c * 8), 16, 0, 0);
        }
        __syncthreads();
        #pragma unroll
        for (int half = 0; half < 2; ++half) {
            int ko = half * 32 + quad * 8;
            bf16x8 afrag[4], bfrag[4];
            #pragma unroll
            for (int mi = 0; mi < 4; ++mi)
                afrag[mi] = *(const bf16x8*)(As + (wr * 64 + mi * 16 + mlane) * 64 + ko);
            #pragma unroll
            for (int ni = 0; ni < 4; ++ni)
                bfrag[ni] = *(const bf16x8*)(Bs + (wc * 64 + ni * 16 + mlane) * 64 + ko);
            #pragma unroll
            for (int mi = 0; mi < 4; ++mi)
                #pragma unroll
                for (int ni = 0; ni < 4; ++ni)
                    acc[mi][ni] = __builtin_amdgcn_mfma_f32_16x16x32_bf16(
                        afrag[mi], bfrag[ni], acc[mi][ni], 0, 0, 0);
        }
    }

    unsigned short* pz = part + (size_t)blockIdx.z * MP * N;
    #pragma unroll
    for (int mi = 0; mi < 4; ++mi) {
        #pragma unroll
        for (int r = 0; r < 4; ++r) {
            int gm = m0 + wr * 64 + mi * 16 + quad * 4 + r;
            size_t rowoff = (size_t)gm * N;
            #pragma unroll
            for (int ni = 0; ni < 4; ++ni) {
                int gn = n0 + wc * 64 + ni * 16 + mlane;
                pz[rowoff + gn] = f2bf(acc[mi][ni][r]);
            }
        }
    }
}

// ---------------------------------------------------------------------------
// bf16 MFMA flash attention, 128-key rounds, fixed-reference softmax,
// register-prefetch pipeline, wave-private XOR-swizzled P round-trip.
// Block = 64 queries x (b,h); 4 waves, each 16 q.
// ---------------------------------------------------------------------------
#define AQT 64
#define NR 9    // rounds of 128 keys over TPAD=1152
__global__ __launch_bounds__(256) void attn_mfma(
    const unsigned short* __restrict__ qb, const unsigned short* __restrict__ kb,
    const unsigned short* __restrict__ vt, unsigned short* __restrict__ ob,
    int qs)
{
    __shared__ unsigned short Ks[128 * 72];    // [key][72]
    __shared__ unsigned short Vs[64 * 136];    // [d][136] keys contiguous
    __shared__ unsigned short Ps[4][16 * 72];
    int bh = blockIdx.y;
    int b = bh >> 3, h = bh & 7;
    int t0 = blockIdx.x * AQT;
    int tid = threadIdx.x;
    int l = tid & 63, w = tid >> 6;
    int ml = l & 15, quad = l >> 4;
    size_t rowbase = (size_t)b * T;
    const unsigned short* vtb = vt + (size_t)bh * 64 * TPAD;

    int qrow = t0 + w * 16 + ml; if (qrow >= T) qrow = T - 1;
    const unsigned short* qp = qb + (rowbase + qrow) * qs + h * HD + quad * 8;
    bf16x8 qf0 = *(const bf16x8*)qp;
    bf16x8 qf1 = *(const bf16x8*)(qp + 32);

    int krow = tid >> 3, kcc = tid & 7;
    int vd   = tid >> 4, vck = tid & 15;

    f32x4 oacc[4] = {};
    float lrow[4] = {0.f, 0.f, 0.f, 0.f};

    bf16x8 kr[4], vr[4];
    #pragma unroll
    for (int i = 0; i < 4; ++i) {
        int gk = krow + i * 32; if (gk >= T) gk = T - 1;
        kr[i] = *(const bf16x8*)(kb + (rowbase + gk) * qs + h * HD + kcc * 8);
        vr[i] = *(const bf16x8*)(vtb + (size_t)(vd + i * 16) * TPAD + vck * 8);
    }

    for (int rnd = 0; rnd < NR; ++rnd) {
        int c0 = rnd * 128;
        __syncthreads();
        #pragma unroll
        for (int i = 0; i < 4; ++i) {
            *(bf16x8*)(Ks + (krow + i * 32) * 72 + kcc * 8) = kr[i];
            *(bf16x8*)(Vs + (vd + i * 16) * 136 + vck * 8) = vr[i];
        }
        __syncthreads();
        if (rnd + 1 < NR) {
            int n0k = c0 + 128;
            #pragma unroll
            for (int i = 0; i < 4; ++i) {
                int gk = n0k + krow + i * 32; if (gk >= T) gk = T - 1;
                kr[i] = *(const bf16x8*)(kb + (rowbase + gk) * qs + h * HD + kcc * 8);
                vr[i] = *(const bf16x8*)(vtb + (size_t)(vd + i * 16) * TPAD + n0k + vck * 8);
            }
        }

        #pragma unroll
        for (int p = 0; p < 2; ++p) {
            int kb0 = p * 64;
            f32x4 s[4] = {};
            #pragma unroll
            for (int ni = 0; ni < 4; ++ni) {
                const unsigned short* kfp = Ks + (kb0 + ni * 16 + ml) * 72 + quad * 8;
                bf16x8 kf0 = *(const bf16x8*)kfp;
                bf16x8 kf1 = *(const bf16x8*)(kfp + 32);
                s[ni] = __builtin_amdgcn_mfma_f32_16x16x32_bf16(qf0, kf0, s[ni], 0, 0, 0);
                s[ni] = __builtin_amdgcn_mfma_f32_16x16x32_bf16(qf1, kf1, s[ni], 0, 0, 0);
            }
            #pragma unroll
            for (int ni = 0; ni < 4; ++ni) {
                bool valid = (c0 + kb0 + ni * 16 + ml) < T;
                #pragma unroll
                for (int r = 0; r < 4; ++r) {
                    float pv = valid ? __expf(s[ni][r] * 0.125f) : 0.f;
                    s[ni][r] = pv;
                    lrow[r] += pv;
                }
            }
            unsigned short* pw = Ps[w];
            #pragma unroll
            for (int r = 0; r < 4; ++r)
                #pragma unroll
                for (int ni = 0; ni < 4; ++ni)
                    pw[(quad * 4 + r) * 72 + ((ni * 16 + ml) ^ (quad << 4))] = f2bf(s[ni][r]);
            int sw = ((ml >> 2) & 3) << 4;
            #pragma unroll
            for (int kc = 0; kc < 2; ++kc) {
                bf16x8 pf = *(const bf16x8*)(pw + ml * 72 + ((kc * 32 + quad * 8) ^ sw));
                #pragma unroll
                for (int ni = 0; ni < 4; ++ni) {
                    bf16x8 vf = *(const bf16x8*)(Vs + (ni * 16 + ml) * 136 + kb0 + kc * 32 + quad * 8);
                    oacc[ni] = __builtin_amdgcn_mfma_f32_16x16x32_bf16(pf, vf, oacc[ni], 0, 0, 0);
                }
            }
        }
    }

    #pragma unroll
    for (int r = 0; r < 4; ++r) {
        #pragma unroll
        for (int off = 1; off < 16; off <<= 1)
            lrow[r] += __shfl_xor(lrow[r], off);
    }
    #pragma unroll
    for (int r = 0; r < 4; ++r) {
        int grow = t0 + w * 16 + quad * 4 + r;
        if (grow >= T) continue;
        float inv = 1.f / lrow[r];
        unsigned short* op = ob + (rowbase + grow) * DM + h * HD;
        #pragma unroll
        for (int ni = 0; ni < 4; ++ni)
            op[ni * 16 + ml] = f2bf(oacc[ni][r] * inv);
    }
}

// ---------------------------------------------------------------------------
// Encoder: writes fp32 h and bf16 shadow hb
// ---------------------------------------------------------------------------
__global__ __launch_bounds__(256) void encoder_kernel(
    const float* __restrict__ x, const float* __restrict__ W_enc,
    const float* __restrict__ b_enc, const float* __restrict__ cls_tok,
    const float* __restrict__ pos_emb, float* __restrict__ h,
    unsigned short* __restrict__ hb)
{
    int row = blockIdx.x;
    int b = row / T, tt = row % T;
    int tid = threadIdx.x;
    float* hp = h + (size_t)row * DM;
    unsigned short* hbp = hb + (size_t)row * DM;
    if (tt == 0) {
        float a0 = cls_tok[tid]       + pos_emb[tid];
        float a1 = cls_tok[tid + 256] + pos_emb[tid + 256];
        hp[tid] = a0; hp[tid + 256] = a1;
        hbp[tid] = f2bf(a0); hbp[tid + 256] = f2bf(a1);
        return;
    }
    __shared__ float xs[NTOK];
    int s = tt - 1;
    if (tid < NTOK) xs[tid] = x[((size_t)b * SEQ + s) * NTOK + tid];
    __syncthreads();
    #pragma unroll
    for (int rep = 0; rep < 2; ++rep) {
        int d = tid + rep * 256;
        float acc = b_enc[d] + pos_emb[(size_t)tt * DM + d];
        for (int kx = 0; kx < NTOK; ++kx) acc += xs[kx] * W_enc[kx * DM + d];
        hp[d] = acc;
        hbp[d] = f2bf(acc);
    }
}

// ---------------------------------------------------------------------------
// Fused (sum of np bf16 partials + bias) residual + LayerNorm, wave-per-row
// ---------------------------------------------------------------------------
__global__ __launch_bounds__(256) void add_lnp_kernel(
    float* __restrict__ h, const unsigned short* __restrict__ part, int np,
    const float* __restrict__ bias, const float* __restrict__ g,
    const float* __restrict__ be, unsigned short* __restrict__ hb)
{
    int w = threadIdx.x >> 6, l = threadIdx.x & 63;
    int row = blockIdx.x * 4 + w;
    if (row >= ROWS) return;
    float* hp = h + (size_t)row * DM + l * 8;
    unsigned short* hbp = hb + (size_t)row * DM + l * 8;
    float4 a0 = *(const float4*)(hp);
    float4 a1 = *(const float4*)(hp + 4);
    float4 b0 = *(const float4*)(bias + l * 8);
    float4 b1 = *(const float4*)(bias + l * 8 + 4);
    float v[8] = {a0.x + b0.x, a0.y + b0.y, a0.z + b0.z, a0.w + b0.w,
                  a1.x + b1.x, a1.y + b1.y, a1.z + b1.z, a1.w + b1.w};
    for (int pp = 0; pp < np; ++pp) {
        const unsigned short* prp = part + ((size_t)pp * MP + row) * DM + l * 8;
        bf16x8 pv = *(const bf16x8*)prp;
        #pragma unroll
        for (int i = 0; i < 8; ++i) v[i] += bf2f((unsigned short)pv[i]);
    }
    float s = 0.f;
    #pragma unroll
    for (int i = 0; i < 8; ++i) s += v[i];
    #pragma unroll
    for (int off = 1; off < 64; off <<= 1) s += __shfl_xor(s, off);
    float mean = s * (1.f / DM);
    float sq = 0.f;
    #pragma unroll
    for (int i = 0; i < 8; ++i) { v[i] -= mean; sq += v[i] * v[i]; }
    #pragma unroll
    for (int off = 1; off < 64; off <<= 1) sq += __shfl_xor(sq, off);
    float inv = rsqrtf(sq * (1.f / DM) + 1e-5f);
    float4 g0 = *(const float4*)(g + l * 8);
    float4 g1 = *(const float4*)(g + l * 8 + 4);
    float4 e0 = *(const float4*)(be + l * 8);
    float4 e1 = *(const float4*)(be + l * 8 + 4);
    float o[8];
    o[0] = v[0]*inv*g0.x + e0.x; o[1] = v[1]*inv*g0.y + e0.y;
    o[2] = v[2]*inv*g0.z + e0.z; o[3] = v[3]*inv*g0.w + e0.w;
    o[4] = v[4]*inv*g1.x + e1.x; o[5] = v[5]*inv*g1.y + e1.y;
    o[6] = v[6]*inv*g1.z + e1.z; o[7] = v[7]*inv*g1.w + e1.w;
    *(float4*)(hp)     = make_float4(o[0], o[1], o[2], o[3]);
    *(float4*)(hp + 4) = make_float4(o[4], o[5], o[6], o[7]);
    ushort4 p0 = {f2bf(o[0]), f2bf(o[1]), f2bf(o[2]), f2bf(o[3])};
    ushort4 p1 = {f2bf(o[4]), f2bf(o[5]), f2bf(o[6]), f2bf(o[7])};
    *(ushort4*)(hbp)     = p0;
    *(ushort4*)(hbp + 4) = p1;
}

// ---------------------------------------------------------------------------
// Decoder stage 1 + stage 2
// ---------------------------------------------------------------------------
__global__ __launch_bounds__(256) void dec1_kernel(
    const float* __restrict__ h, const float* __restrict__ Wd1,
    float* __restrict__ part)
{
    int kc = blockIdx.x, b = blockIdx.y, tid = threadIdx.x;
    __shared__ float cs[64];
    const float* cls = h + (size_t)b * T * DM;
    if (tid < 64) cs[tid] = cls[kc * 64 + tid];
    __syncthreads();
    float acc = 0.f;
    #pragma unroll
    for (int kx = 0; kx < 64; ++kx)
        acc += cs[kx] * Wd1[(size_t)(kc * 64 + kx) * MLPDIM + tid];
    part[(size_t)(b * 8 + kc) * MLPDIM + tid] = acc;
}

__global__ __launch_bounds__(256) void dec2_kernel(
    const float* __restrict__ part, const float* __restrict__ bd1,
    const float* __restrict__ Wd2, const float* __restrict__ bd2,
    float* __restrict__ out)
{
    __shared__ float t1s[MLPDIM];
    int tid = threadIdx.x;
    for (int b = 0; b < NBATCH; ++b) {
        float acc = bd1[tid];
        #pragma unroll
        for (int kc = 0; kc < 8; ++kc)
            acc += part[(size_t)(b * 8 + kc) * MLPDIM + tid];
        t1s[tid] = acc;
        __syncthreads();
        if (tid < NCLS) {
            float a2 = bd2[tid];
            for (int kx = 0; kx < MLPDIM; ++kx) a2 += t1s[kx] * Wd2[kx * NCLS + tid];
            out[b * NCLS + tid] = a2;
        }
        __syncthreads();
    }
}

// ---------------------------------------------------------------------------
// GAT: 4 graphs per 256-thread block (one per wave). 1280 blocks.
// ---------------------------------------------------------------------------
__global__ __launch_bounds__(256) void gat_kernel(
    const float* __restrict__ x, const int* __restrict__ adj,
    const float* __restrict__ Wg, const float* __restrict__ ag,
    const float* __restrict__ Wgo, const float* __restrict__ ago,
    float* __restrict__ out)
{
    int w4 = threadIdx.x >> 6;
    int tid = threadIdx.x & 63;
    int g = blockIdx.x * 4 + w4;
    int s = g / 5, jj = g % 5;
    __shared__ float xs[4][5][3];
    __shared__ int adjs[4][25];
    __shared__ float hb[4][GH][5][GHID];
    __shared__ float o1[4][GH][5][GHID];
    __shared__ float srcb[4][GH][5], dstb[4][GH][5];
    __shared__ float attb[4][GH][5][5];
    __shared__ float h2[4][5][5], src2[4][5], dst2[4][5], att2[4][5][5], o2[4][5][5];

    if (tid < 15) { int n = tid / 3, c = tid % 3;
        xs[w4][n][c] = x[(size_t)n * SEQ * NTOK + (size_t)s * NTOK + jj * 3 + c]; }
    if (tid < 25) adjs[w4][tid] = adj[tid];
    __syncthreads();

    #pragma unroll
    for (int hh = 0; hh < GH; ++hh)
        #pragma unroll
        for (int n = 0; n < 5; ++n)
            hb[w4][hh][n][tid] = xs[w4][n][0] * Wg[hh * 192 + tid]
                               + xs[w4][n][1] * Wg[hh * 192 + 64 + tid]
                               + xs[w4][n][2] * Wg[hh * 192 + 128 + tid];
    __syncthreads();

    if (tid < 15) { int hh = tid / 5, n = tid % 5; float a = 0.f;
        for (int f = 0; f < GHID; ++f) a += hb[w4][hh][n][f] * ag[hh * 128 + f];
        srcb[w4][hh][n] = a;
    } else if (tid >= 32 && tid < 47) { int t2 = tid - 32; int hh = t2 / 5, n = t2 % 5; float a = 0.f;
        for (int f = 0; f < GHID; ++f) a += hb[w4][hh][n][f] * ag[hh * 128 + 64 + f];
        dstb[w4][hh][n] = a;
    }
    __syncthreads();

    if (tid < 15) { int hh = tid / 5, i = tid % 5;
        float e[5]; float mx = -1e30f;
        #pragma unroll
        for (int j2 = 0; j2 < 5; ++j2) {
            float ev = srcb[w4][hh][i] + dstb[w4][hh][j2];
            ev = ev > 0.f ? ev : 0.2f * ev;
            e[j2] = ev;
            if (adjs[w4][i * 5 + j2] && ev > mx) mx = ev;
        }
        float sum = 0.f;
        #pragma unroll
        for (int j2 = 0; j2 < 5; ++j2) {
            float p = adjs[w4][i * 5 + j2] ? expf(e[j2] - mx) : 0.f;
            e[j2] = p; sum += p;
        }
        float inv = 1.f / sum;
        #pragma unroll
        for (int j2 = 0; j2 < 5; ++j2) attb[w4][hh][i][j2] = e[j2] * inv;
    }
    __syncthreads();

    #pragma unroll
    for (int hh = 0; hh < GH; ++hh)
        #pragma unroll
        for (int n = 0; n < 5; ++n) {
            float a = 0.f;
            #pragma unroll
            for (int j2 = 0; j2 < 5; ++j2) a += attb[w4][hh][n][j2] * hb[w4][hh][j2][tid];
            o1[w4][hh][n][tid] = a > 0.f ? a : expm1f(a);
        }
    __syncthreads();

    if (tid < 25) { int n = tid / 5, m = tid % 5; float a = 0.f;
        for (int hh = 0; hh < GH; ++hh)
            for (int f = 0; f < GHID; ++f)
                a += o1[w4][hh][n][f] * Wgo[(hh * GHID + f) * GCLS + m];
        h2[w4][n][m] = a;
    }
    __syncthreads();

    if (tid < 5) { float a = 0.f;
        for (int m = 0; m < GCLS; ++m) a += h2[w4][tid][m] * ago[m];
        src2[w4][tid] = a;
    } else if (tid >= 8 && tid < 13) { int n = tid - 8; float a = 0.f;
        for (int m = 0; m < GCLS; ++m) a += h2[w4][n][m] * ago[GCLS + m];
        dst2[w4][n] = a;
    }
    __syncthreads();

    if (tid < 5) { int i = tid;
        float e[5]; float mx = -1e30f;
        #pragma unroll
        for (int j2 = 0; j2 < 5; ++j2) {
            float ev = src2[w4][i] + dst2[w4][j2];
            ev = ev > 0.f ? ev : 0.2f * ev;
            e[j2] = ev;
            if (adjs[w4][i * 5 + j2] && ev > mx) mx = ev;
        }
        float sum = 0.f;
        #pragma unroll
        for (int j2 = 0; j2 < 5; ++j2) {
            float p = adjs[w4][i * 5 + j2] ? expf(e[j2] - mx) : 0.f;
            e[j2] = p; sum += p;
        }
        float inv = 1.f / sum;
        #pragma unroll
        for (int j2 = 0; j2 < 5; ++j2) att2[w4][i][j2] = e[j2] * inv;
    }
    __syncthreads();

    if (tid < 25) { int n = tid / 5, m = tid % 5; float a = 0.f;
        #pragma unroll
        for (int j2 = 0; j2 < 5; ++j2) a += att2[w4][n][j2] * h2[w4][j2][m];
        o2[w4][n][m] = a > 0.f ? a : expm1f(a);
    }
    __syncthreads();

    if (tid < 5) { int n = tid;
        float mx = o2[w4][n][0];
        #pragma unroll
        for (int m = 1; m < GCLS; ++m) mx = fmaxf(mx, o2[w4][n][m]);
        float sum = 0.f;
        #pragma unroll
        for (int m = 0; m < GCLS; ++m) sum += expf(o2[w4][n][m] - mx);
        float ls = logf(sum);
        #pragma unroll
        for (int m = 0; m < GCLS; ++m)
            out[(size_t)g * 25 + n * 5 + m] = o2[w4][n][m] - mx - ls;
    }
}

// ---------------------------------------------------------------------------
// Launch
// ---------------------------------------------------------------------------
extern "C" void kernel_launch(void* const* d_in, const int* in_sizes, int n_in,
                              void* d_out, int out_size, void* d_ws, size_t ws_size,
                              hipStream_t stream)
{
    const float* x       = (const float*)d_in[0];
    const int*   adj     = (const int*)  d_in[1];
    const float* W_enc   = (const float*)d_in[2];
    const float* b_enc   = (const float*)d_in[3];
    const float* cls_tok = (const float*)d_in[4];
    const float* pos_emb = (const float*)d_in[5];
    const float* Wq = (const float*)d_in[6];
    const float* bq = (const float*)d_in[7];
    const float* Wk = (const float*)d_in[8];
    const float* bk = (const float*)d_in[9];
    const float* Wv = (const float*)d_in[10];
    const float* bv = (const float*)d_in[11];
    const float* Wo = (const float*)d_in[12];
    const float* bo = (const float*)d_in[13];
    const float* W1 = (const float*)d_in[14];
    const float* b1 = (const float*)d_in[15];
    const float* W2 = (const float*)d_in[16];
    const float* b2 = (const float*)d_in[17];
    const float* g1 = (const float*)d_in[18];
    const float* be1= (const float*)d_in[19];
    const float* g2 = (const float*)d_in[20];
    const float* be2= (const float*)d_in[21];
    const float* Wd1= (const float*)d_in[22];
    const float* bd1= (const float*)d_in[23];
    const float* Wd2= (const float*)d_in[24];
    const float* bd2= (const float*)d_in[25];
    const float* Wg = (const float*)d_in[26];
    const float* ag = (const float*)d_in[27];
    const float* Wgo= (const float*)d_in[28];
    const float* ago= (const float*)d_in[29];
    float* out = (float*)d_out;

    // workspace layout (~91 MB)
    float* ws = (float*)d_ws;
    float* h = ws;
    unsigned short* hb   = (unsigned short*)(h + (size_t)MP * DM);
    unsigned short* qkvb = hb + (size_t)MP * DM;
    unsigned short* ob   = qkvb + (size_t)MP * QKVN;
    unsigned short* f1b  = qkvb;                    // alias qkvb+ob
    unsigned short* Wqkvt= ob + (size_t)MP * DM;
    unsigned short* Wot  = Wqkvt + (size_t)4 * QKVN * DM;
    unsigned short* W1t  = Wot + (size_t)4 * DM * DM;
    unsigned short* W2t  = W1t + (size_t)4 * DM * DFF;
    float* bqkv = (float*)(W2t + (size_t)4 * DFF * DM);
    float* dpart = bqkv + 4 * QKVN;
    unsigned short* vt = (unsigned short*)(dpart + NBATCH * 8 * MLPDIM);  // [40][64][TPAD]
    unsigned short* parts = vt + (size_t)40 * 64 * TPAD;   // [4][MP][512] bf16

    setup_kernel<<<12292, 256, 0, stream>>>(Wq, Wk, Wv, Wo, W1, W2, bq, bk, bv,
                                            Wqkvt, Wot, W1t, W2t, bqkv);

    gat_kernel<<<NGRAPH / 4, 256, 0, stream>>>(x, adj, Wg, ag, Wgo, ago, out + NBATCH * NCLS);
    encoder_kernel<<<ROWS, 256, 0, stream>>>(x, W_enc, b_enc, cls_tok, pos_emb, h, hb);

    dim3 gqkv (QKVN / 128, MP / 128);        // (12, 41)
    dim3 g2048(DFF / 128, MP / 128);         // (16, 41)
    dim3 gWo  (DM / 128, MP / 128, 2);       // split-K=2
    dim3 gW2  (DM / 128, MP / 128, 4);       // split-K=4
    dim3 gAttn(17, NBATCH * NHEAD);          // 17 q-tiles x 40 bh
    int gLN = (ROWS + 3) / 4;

    for (int i = 0; i < 4; ++i) {
        gemm_mfma<<<gqkv, 256, 0, stream>>>(hb, Wqkvt + (size_t)i*QKVN*DM, bqkv + i*QKVN, nullptr, qkvb, vt, QKVN, DM, 0);
        attn_mfma<<<gAttn, 256, 0, stream>>>(qkvb, qkvb + 512, vt, ob, QKVN);
        gemm_mfma_sk<<<gWo, 256, 0, stream>>>(ob, Wot + (size_t)i*DM*DM, parts, DM, DM);
        add_lnp_kernel<<<gLN, 256, 0, stream>>>(h, parts, 2, bo + i*DM, g1 + i*DM, be1 + i*DM, hb);
        gemm_mfma<<<g2048, 256, 0, stream>>>(hb,  W1t + (size_t)i*DM*DFF, b1 + i*DFF, nullptr, f1b, nullptr, DFF, DM, 1);
        gemm_mfma_sk<<<gW2, 256, 0, stream>>>(f1b, W2t + (size_t)i*DM*DFF, parts, DM, DFF);
        add_lnp_kernel<<<gLN, 256, 0, stream>>>(h, parts, 4, b2 + i*DM, g2 + i*DM, be2 + i*DM, hb);
    }

    dec1_kernel<<<dim3(8, NBATCH), 256, 0, stream>>>(h, Wd1, dpart);
    dec2_kernel<<<1, 256, 0, stream>>>(dpart, bd1, Wd2, bd2, out);
}

// Round 12
// 795.654 us; speedup vs baseline: 1.0419x; 1.0419x over previous
//
#include <hip/hip_runtime.h>
#include <hip/hip_bf16.h>
#include <math.h>

// ---------------------------------------------------------------------------
// Model constants
// ---------------------------------------------------------------------------
#define NBATCH 5
#define SEQ    1024
#define T      1025          // SEQ + 1 (cls token)
#define ROWS   (NBATCH * T)  // 5125
#define MP     5248          // ROWS padded to 41*128 for MFMA tiles
#define DM     512
#define DFF    2048
#define NHEAD  8
#define HD     64
#define NTOK   51
#define MLPDIM 256
#define NCLS   7
#define GH     3
#define GHID   64
#define GCLS   5
#define NGRAPH (SEQ * 5)     // 5120
#define QKVN   1536          // fused QKV output width
#define TPAD   1152          // T padded to 9*128 for V^T buffer

typedef __attribute__((ext_vector_type(8))) short bf16x8;
typedef __attribute__((ext_vector_type(4))) float f32x4;

#define GM_AS(p)  ((const __attribute__((address_space(1))) void*)(p))
#define LDS_AS(p) ((__attribute__((address_space(3))) void*)(p))

__device__ __forceinline__ unsigned short f2bf(float f) {
    unsigned int u = __float_as_uint(f);
    unsigned int r = (u + 0x7FFFu + ((u >> 16) & 1u)) >> 16;
    return (unsigned short)r;
}
__device__ __forceinline__ float bf2f(unsigned short u) {
    return __uint_as_float((unsigned int)u << 16);
}

// ---------------------------------------------------------------------------
// Mega-setup: all weight transposes (fp32->bf16, [K][N]->[N][K]) + bias concat.
// ---------------------------------------------------------------------------
__global__ __launch_bounds__(256) void setup_kernel(
    const float* __restrict__ Wq, const float* __restrict__ Wk,
    const float* __restrict__ Wv, const float* __restrict__ Wo_,
    const float* __restrict__ W1, const float* __restrict__ W2,
    const float* __restrict__ bq, const float* __restrict__ bk,
    const float* __restrict__ bv,
    unsigned short* __restrict__ Wqkvt, unsigned short* __restrict__ Wot,
    unsigned short* __restrict__ W1t, unsigned short* __restrict__ W2t,
    float* __restrict__ bqkv)
{
    int id = blockIdx.x;
    if (id >= 12288) {              // bias concat: 4 blocks, one per layer
        int i = id - 12288;
        #pragma unroll
        for (int rep = 0; rep < 2; ++rep) {
            int t = threadIdx.x + rep * 256;
            bqkv[i * QKVN + t]        = bq[i * DM + t];
            bqkv[i * QKVN + 512 + t]  = bk[i * DM + t];
            bqkv[i * QKVN + 1024 + t] = bv[i * DM + t];
        }
        return;
    }
    const float* W; unsigned short* Wt; int K, N, z, bx, by; long dstride;
    if (id < 4096) {                // Wq/Wk/Wv/Wo: 512x512
        int g = id >> 10, lid = id & 1023;
        K = DM; N = DM;
        z = lid >> 8; int r2 = lid & 255; by = r2 >> 4; bx = r2 & 15;
        if (g < 3) { W = (g == 0) ? Wq : (g == 1) ? Wk : Wv;
                     Wt = Wqkvt + (size_t)g * DM * DM; dstride = (long)QKVN * DM; }
        else       { W = Wo_; Wt = Wot; dstride = (long)DM * DM; }
    } else if (id < 8192) {         // W1: K=512, N=2048
        int lid = id - 4096;
        K = DM; N = DFF;
        z = lid >> 10; int r2 = lid & 1023; by = r2 >> 6; bx = r2 & 63;
        W = W1; Wt = W1t; dstride = (long)DM * DFF;
    } else {                        // W2: K=2048, N=512
        int lid = id - 8192;
        K = DFF; N = DM;
        z = lid >> 10; int r2 = lid & 1023; by = r2 >> 4; bx = r2 & 15;
        W = W2; Wt = W2t; dstride = (long)DFF * DM;
    }
    const float* Wm = W + (size_t)z * K * N;
    unsigned short* Wo2 = Wt + (size_t)z * dstride;
    __shared__ float tile[32][33];
    int bX = bx * 32, bY = by * 32;
    int tx = threadIdx.x & 31, ty = threadIdx.x >> 5;
    #pragma unroll
    for (int i = 0; i < 32; i += 8)
        tile[ty + i][tx] = Wm[(size_t)(bY + ty + i) * N + bX + tx];
    __syncthreads();
    #pragma unroll
    for (int i = 0; i < 32; i += 8)
        Wo2[(size_t)(bX + ty + i) * K + bY + tx] = f2bf(tile[tx][ty + i]);
}

// ---------------------------------------------------------------------------
// bf16 MFMA GEMM: C[M][N] = A[M][K] @ Bt[N][K]^T + bias. 128x128 tile, BK=64.
// ---------------------------------------------------------------------------
__global__ __launch_bounds__(256) void gemm_mfma(
    const unsigned short* __restrict__ A, const unsigned short* __restrict__ Bt,
    const float* __restrict__ bias, float* __restrict__ Cf,
    unsigned short* __restrict__ Cb, int N, int K, int relu)
{
    __shared__ unsigned short As[128 * 64];
    __shared__ unsigned short Bs[128 * 64];
    int tid = threadIdx.x;
    int l = tid & 63, w = tid >> 6;
    int wr = w & 1, wc = w >> 1;
    int mlane = l & 15, quad = l >> 4;
    int m0 = blockIdx.y * 128, n0 = blockIdx.x * 128;

    f32x4 acc[4][4] = {};

    for (int k0 = 0; k0 < K; k0 += 64) {
        __syncthreads();
        #pragma unroll
        for (int it = 0; it < 4; ++it) {
            int c = tid + it * 256;
            int row = c >> 3, cc = c & 7;
            const unsigned short* ga = A  + (size_t)(m0 + row) * K + k0 + cc * 8;
            __builtin_amdgcn_global_load_lds(GM_AS(ga), LDS_AS(As + c * 8), 16, 0, 0);
            const unsigned short* gb = Bt + (size_t)(n0 + row) * K + k0 + cc * 8;
            __builtin_amdgcn_global_load_lds(GM_AS(gb), LDS_AS(Bs + c * 8), 16, 0, 0);
        }
        __syncthreads();
        #pragma unroll
        for (int half = 0; half < 2; ++half) {
            int ko = half * 32 + quad * 8;
            bf16x8 afrag[4], bfrag[4];
            #pragma unroll
            for (int mi = 0; mi < 4; ++mi)
                afrag[mi] = *(const bf16x8*)(As + (wr * 64 + mi * 16 + mlane) * 64 + ko);
            #pragma unroll
            for (int ni = 0; ni < 4; ++ni)
                bfrag[ni] = *(const bf16x8*)(Bs + (wc * 64 + ni * 16 + mlane) * 64 + ko);
            #pragma unroll
            for (int mi = 0; mi < 4; ++mi)
                #pragma unroll
                for (int ni = 0; ni < 4; ++ni)
                    acc[mi][ni] = __builtin_amdgcn_mfma_f32_16x16x32_bf16(
                        afrag[mi], bfrag[ni], acc[mi][ni], 0, 0, 0);
        }
    }

    #pragma unroll
    for (int mi = 0; mi < 4; ++mi) {
        #pragma unroll
        for (int r = 0; r < 4; ++r) {
            int gm = m0 + wr * 64 + mi * 16 + quad * 4 + r;
            size_t rowoff = (size_t)gm * N;
            #pragma unroll
            for (int ni = 0; ni < 4; ++ni) {
                int gn = n0 + wc * 64 + ni * 16 + mlane;
                float val = acc[mi][ni][r] + bias[gn];
                if (relu) val = fmaxf(val, 0.f);
                if (Cb) Cb[rowoff + gn] = f2bf(val);
                else    Cf[rowoff + gn] = val;
            }
        }
    }
}

// ---------------------------------------------------------------------------
// Split-K bf16 MFMA GEMM: writes bf16 partials; combined in add_lnp.
// ---------------------------------------------------------------------------
__global__ __launch_bounds__(256) void gemm_mfma_sk(
    const unsigned short* __restrict__ A, const unsigned short* __restrict__ Bt,
    unsigned short* __restrict__ part, int N, int K)
{
    __shared__ unsigned short As[128 * 64];
    __shared__ unsigned short Bs[128 * 64];
    int tid = threadIdx.x;
    int l = tid & 63, w = tid >> 6;
    int wr = w & 1, wc = w >> 1;
    int mlane = l & 15, quad = l >> 4;
    int m0 = blockIdx.y * 128, n0 = blockIdx.x * 128;
    int kper = K / gridDim.z;
    int kbeg = blockIdx.z * kper;

    f32x4 acc[4][4] = {};

    for (int k0 = kbeg; k0 < kbeg + kper; k0 += 64) {
        __syncthreads();
        #pragma unroll
        for (int it = 0; it < 4; ++it) {
            int c = tid + it * 256;
            int row = c >> 3, cc = c & 7;
            const unsigned short* ga = A  + (size_t)(m0 + row) * K + k0 + cc * 8;
            __builtin_amdgcn_global_load_lds(GM_AS(ga), LDS_AS(As + c * 8), 16, 0, 0);
            const unsigned short* gb = Bt + (size_t)(n0 + row) * K + k0 + cc * 8;
            __builtin_amdgcn_global_load_lds(GM_AS(gb), LDS_AS(Bs + c * 8), 16, 0, 0);
        }
        __syncthreads();
        #pragma unroll
        for (int half = 0; half < 2; ++half) {
            int ko = half * 32 + quad * 8;
            bf16x8 afrag[4], bfrag[4];
            #pragma unroll
            for (int mi = 0; mi < 4; ++mi)
                afrag[mi] = *(const bf16x8*)(As + (wr * 64 + mi * 16 + mlane) * 64 + ko);
            #pragma unroll
            for (int ni = 0; ni < 4; ++ni)
                bfrag[ni] = *(const bf16x8*)(Bs + (wc * 64 + ni * 16 + mlane) * 64 + ko);
            #pragma unroll
            for (int mi = 0; mi < 4; ++mi)
                #pragma unroll
                for (int ni = 0; ni < 4; ++ni)
                    acc[mi][ni] = __builtin_amdgcn_mfma_f32_16x16x32_bf16(
                        afrag[mi], bfrag[ni], acc[mi][ni], 0, 0, 0);
        }
    }

    unsigned short* pz = part + (size_t)blockIdx.z * MP * N;
    #pragma unroll
    for (int mi = 0; mi < 4; ++mi) {
        #pragma unroll
        for (int r = 0; r < 4; ++r) {
            int gm = m0 + wr * 64 + mi * 16 + quad * 4 + r;
            size_t rowoff = (size_t)gm * N;
            #pragma unroll
            for (int ni = 0; ni < 4; ++ni) {
                int gn = n0 + wc * 64 + ni * 16 + mlane;
                pz[rowoff + gn] = f2bf(acc[mi][ni][r]);
            }
        }
    }
}

// ---------------------------------------------------------------------------
// V transpose per layer: vb rows (b,t) stride qs -> vt[(bh*64+d)][TPAD].
// ---------------------------------------------------------------------------
__global__ __launch_bounds__(256) void vtrans_kernel(
    const unsigned short* __restrict__ vb, unsigned short* __restrict__ vt, int qs)
{
    __shared__ unsigned short tile[64][72];
    int bh = blockIdx.y;
    int b = bh >> 3, h = bh & 7;
    int t0 = blockIdx.x * 64;
    int tid = threadIdx.x;
    #pragma unroll
    for (int it = 0; it < 2; ++it) {
        int c = tid + it * 256;
        int key = c >> 3, cc = c & 7;
        int gk = t0 + key; if (gk >= T) gk = T - 1;
        *(bf16x8*)(&tile[key][cc * 8]) =
            *(const bf16x8*)(vb + ((size_t)b * T + gk) * qs + h * HD + cc * 8);
    }
    __syncthreads();
    #pragma unroll
    for (int it = 0; it < 2; ++it) {
        int c = tid + it * 256;
        int d = c >> 3, cc = c & 7;
        unsigned short tmp[8];
        #pragma unroll
        for (int j = 0; j < 8; ++j) tmp[j] = tile[cc * 8 + j][d];
        *(bf16x8*)(vt + ((size_t)bh * 64 + d) * TPAD + t0 + cc * 8) = *(bf16x8*)tmp;
    }
}

// ---------------------------------------------------------------------------
// bf16 MFMA flash attention, 128-key rounds, fixed-reference softmax,
// register-prefetch pipeline, wave-private XOR-swizzled P round-trip.
// Block = 64 queries x (b,h); 4 waves, each 16 q.
// ---------------------------------------------------------------------------
#define AQT 64
#define NR 9    // rounds of 128 keys over TPAD=1152
__global__ __launch_bounds__(256) void attn_mfma(
    const unsigned short* __restrict__ qb, const unsigned short* __restrict__ kb,
    const unsigned short* __restrict__ vt, unsigned short* __restrict__ ob,
    int qs)
{
    __shared__ unsigned short Ks[128 * 72];    // [key][72]
    __shared__ unsigned short Vs[64 * 136];    // [d][136] keys contiguous
    __shared__ unsigned short Ps[4][16 * 72];
    int bh = blockIdx.y;
    int b = bh >> 3, h = bh & 7;
    int t0 = blockIdx.x * AQT;
    int tid = threadIdx.x;
    int l = tid & 63, w = tid >> 6;
    int ml = l & 15, quad = l >> 4;
    size_t rowbase = (size_t)b * T;
    const unsigned short* vtb = vt + (size_t)bh * 64 * TPAD;

    int qrow = t0 + w * 16 + ml; if (qrow >= T) qrow = T - 1;
    const unsigned short* qp = qb + (rowbase + qrow) * qs + h * HD + quad * 8;
    bf16x8 qf0 = *(const bf16x8*)qp;
    bf16x8 qf1 = *(const bf16x8*)(qp + 32);

    int krow = tid >> 3, kcc = tid & 7;
    int vd   = tid >> 4, vck = tid & 15;

    f32x4 oacc[4] = {};
    float lrow[4] = {0.f, 0.f, 0.f, 0.f};

    bf16x8 kr[4], vr[4];
    #pragma unroll
    for (int i = 0; i < 4; ++i) {
        int gk = krow + i * 32; if (gk >= T) gk = T - 1;
        kr[i] = *(const bf16x8*)(kb + (rowbase + gk) * qs + h * HD + kcc * 8);
        vr[i] = *(const bf16x8*)(vtb + (size_t)(vd + i * 16) * TPAD + vck * 8);
    }

    for (int rnd = 0; rnd < NR; ++rnd) {
        int c0 = rnd * 128;
        __syncthreads();
        #pragma unroll
        for (int i = 0; i < 4; ++i) {
            *(bf16x8*)(Ks + (krow + i * 32) * 72 + kcc * 8) = kr[i];
            *(bf16x8*)(Vs + (vd + i * 16) * 136 + vck * 8) = vr[i];
        }
        __syncthreads();
        if (rnd + 1 < NR) {
            int n0k = c0 + 128;
            #pragma unroll
            for (int i = 0; i < 4; ++i) {
                int gk = n0k + krow + i * 32; if (gk >= T) gk = T - 1;
                kr[i] = *(const bf16x8*)(kb + (rowbase + gk) * qs + h * HD + kcc * 8);
                vr[i] = *(const bf16x8*)(vtb + (size_t)(vd + i * 16) * TPAD + n0k + vck * 8);
            }
        }

        #pragma unroll
        for (int p = 0; p < 2; ++p) {
            int kb0 = p * 64;
            f32x4 s[4] = {};
            #pragma unroll
            for (int ni = 0; ni < 4; ++ni) {
                const unsigned short* kfp = Ks + (kb0 + ni * 16 + ml) * 72 + quad * 8;
                bf16x8 kf0 = *(const bf16x8*)kfp;
                bf16x8 kf1 = *(const bf16x8*)(kfp + 32);
                s[ni] = __builtin_amdgcn_mfma_f32_16x16x32_bf16(qf0, kf0, s[ni], 0, 0, 0);
                s[ni] = __builtin_amdgcn_mfma_f32_16x16x32_bf16(qf1, kf1, s[ni], 0, 0, 0);
            }
            #pragma unroll
            for (int ni = 0; ni < 4; ++ni) {
                bool valid = (c0 + kb0 + ni * 16 + ml) < T;
                #pragma unroll
                for (int r = 0; r < 4; ++r) {
                    float pv = valid ? __expf(s[ni][r] * 0.125f) : 0.f;
                    s[ni][r] = pv;
                    lrow[r] += pv;
                }
            }
            unsigned short* pw = Ps[w];
            #pragma unroll
            for (int r = 0; r < 4; ++r)
                #pragma unroll
                for (int ni = 0; ni < 4; ++ni)
                    pw[(quad * 4 + r) * 72 + ((ni * 16 + ml) ^ (quad << 4))] = f2bf(s[ni][r]);
            int sw = ((ml >> 2) & 3) << 4;
            #pragma unroll
            for (int kc = 0; kc < 2; ++kc) {
                bf16x8 pf = *(const bf16x8*)(pw + ml * 72 + ((kc * 32 + quad * 8) ^ sw));
                #pragma unroll
                for (int ni = 0; ni < 4; ++ni) {
                    bf16x8 vf = *(const bf16x8*)(Vs + (ni * 16 + ml) * 136 + kb0 + kc * 32 + quad * 8);
                    oacc[ni] = __builtin_amdgcn_mfma_f32_16x16x32_bf16(pf, vf, oacc[ni], 0, 0, 0);
                }
            }
        }
    }

    #pragma unroll
    for (int r = 0; r < 4; ++r) {
        #pragma unroll
        for (int off = 1; off < 16; off <<= 1)
            lrow[r] += __shfl_xor(lrow[r], off);
    }
    #pragma unroll
    for (int r = 0; r < 4; ++r) {
        int grow = t0 + w * 16 + quad * 4 + r;
        if (grow >= T) continue;
        float inv = 1.f / lrow[r];
        unsigned short* op = ob + (rowbase + grow) * DM + h * HD;
        #pragma unroll
        for (int ni = 0; ni < 4; ++ni)
            op[ni * 16 + ml] = f2bf(oacc[ni][r] * inv);
    }
}

// ---------------------------------------------------------------------------
// Encoder: writes fp32 h and bf16 shadow hb
// ---------------------------------------------------------------------------
__global__ __launch_bounds__(256) void encoder_kernel(
    const float* __restrict__ x, const float* __restrict__ W_enc,
    const float* __restrict__ b_enc, const float* __restrict__ cls_tok,
    const float* __restrict__ pos_emb, float* __restrict__ h,
    unsigned short* __restrict__ hb)
{
    int row = blockIdx.x;
    int b = row / T, tt = row % T;
    int tid = threadIdx.x;
    float* hp = h + (size_t)row * DM;
    unsigned short* hbp = hb + (size_t)row * DM;
    if (tt == 0) {
        float a0 = cls_tok[tid]       + pos_emb[tid];
        float a1 = cls_tok[tid + 256] + pos_emb[tid + 256];
        hp[tid] = a0; hp[tid + 256] = a1;
        hbp[tid] = f2bf(a0); hbp[tid + 256] = f2bf(a1);
        return;
    }
    __shared__ float xs[NTOK];
    int s = tt - 1;
    if (tid < NTOK) xs[tid] = x[((size_t)b * SEQ + s) * NTOK + tid];
    __syncthreads();
    #pragma unroll
    for (int rep = 0; rep < 2; ++rep) {
        int d = tid + rep * 256;
        float acc = b_enc[d] + pos_emb[(size_t)tt * DM + d];
        for (int kx = 0; kx < NTOK; ++kx) acc += xs[kx] * W_enc[kx * DM + d];
        hp[d] = acc;
        hbp[d] = f2bf(acc);
    }
}

// ---------------------------------------------------------------------------
// Fused (sum of np bf16 partials + bias) residual + LayerNorm, wave-per-row
// ---------------------------------------------------------------------------
__global__ __launch_bounds__(256) void add_lnp_kernel(
    float* __restrict__ h, const unsigned short* __restrict__ part, int np,
    const float* __restrict__ bias, const float* __restrict__ g,
    const float* __restrict__ be, unsigned short* __restrict__ hb)
{
    int w = threadIdx.x >> 6, l = threadIdx.x & 63;
    int row = blockIdx.x * 4 + w;
    if (row >= ROWS) return;
    float* hp = h + (size_t)row * DM + l * 8;
    unsigned short* hbp = hb + (size_t)row * DM + l * 8;
    float4 a0 = *(const float4*)(hp);
    float4 a1 = *(const float4*)(hp + 4);
    float4 b0 = *(const float4*)(bias + l * 8);
    float4 b1 = *(const float4*)(bias + l * 8 + 4);
    float v[8] = {a0.x + b0.x, a0.y + b0.y, a0.z + b0.z, a0.w + b0.w,
                  a1.x + b1.x, a1.y + b1.y, a1.z + b1.z, a1.w + b1.w};
    for (int pp = 0; pp < np; ++pp) {
        const unsigned short* prp = part + ((size_t)pp * MP + row) * DM + l * 8;
        bf16x8 pv = *(const bf16x8*)prp;
        #pragma unroll
        for (int i = 0; i < 8; ++i) v[i] += bf2f((unsigned short)pv[i]);
    }
    float s = 0.f;
    #pragma unroll
    for (int i = 0; i < 8; ++i) s += v[i];
    #pragma unroll
    for (int off = 1; off < 64; off <<= 1) s += __shfl_xor(s, off);
    float mean = s * (1.f / DM);
    float sq = 0.f;
    #pragma unroll
    for (int i = 0; i < 8; ++i) { v[i] -= mean; sq += v[i] * v[i]; }
    #pragma unroll
    for (int off = 1; off < 64; off <<= 1) sq += __shfl_xor(sq, off);
    float inv = rsqrtf(sq * (1.f / DM) + 1e-5f);
    float4 g0 = *(const float4*)(g + l * 8);
    float4 g1 = *(const float4*)(g + l * 8 + 4);
    float4 e0 = *(const float4*)(be + l * 8);
    float4 e1 = *(const float4*)(be + l * 8 + 4);
    float o[8];
    o[0] = v[0]*inv*g0.x + e0.x; o[1] = v[1]*inv*g0.y + e0.y;
    o[2] = v[2]*inv*g0.z + e0.z; o[3] = v[3]*inv*g0.w + e0.w;
    o[4] = v[4]*inv*g1.x + e1.x; o[5] = v[5]*inv*g1.y + e1.y;
    o[6] = v[6]*inv*g1.z + e1.z; o[7] = v[7]*inv*g1.w + e1.w;
    *(float4*)(hp)     = make_float4(o[0], o[1], o[2], o[3]);
    *(float4*)(hp + 4) = make_float4(o[4], o[5], o[6], o[7]);
    ushort4 p0 = {f2bf(o[0]), f2bf(o[1]), f2bf(o[2]), f2bf(o[3])};
    ushort4 p1 = {f2bf(o[4]), f2bf(o[5]), f2bf(o[6]), f2bf(o[7])};
    *(ushort4*)(hbp)     = p0;
    *(ushort4*)(hbp + 4) = p1;
}

// ---------------------------------------------------------------------------
// Decoder stage 1 + stage 2
// ---------------------------------------------------------------------------
__global__ __launch_bounds__(256) void dec1_kernel(
    const float* __restrict__ h, const float* __restrict__ Wd1,
    float* __restrict__ part)
{
    int kc = blockIdx.x, b = blockIdx.y, tid = threadIdx.x;
    __shared__ float cs[64];
    const float* cls = h + (size_t)b * T * DM;
    if (tid < 64) cs[tid] = cls[kc * 64 + tid];
    __syncthreads();
    float acc = 0.f;
    #pragma unroll
    for (int kx = 0; kx < 64; ++kx)
        acc += cs[kx] * Wd1[(size_t)(kc * 64 + kx) * MLPDIM + tid];
    part[(size_t)(b * 8 + kc) * MLPDIM + tid] = acc;
}

__global__ __launch_bounds__(256) void dec2_kernel(
    const float* __restrict__ part, const float* __restrict__ bd1,
    const float* __restrict__ Wd2, const float* __restrict__ bd2,
    float* __restrict__ out)
{
    __shared__ float t1s[MLPDIM];
    int tid = threadIdx.x;
    for (int b = 0; b < NBATCH; ++b) {
        float acc = bd1[tid];
        #pragma unroll
        for (int kc = 0; kc < 8; ++kc)
            acc += part[(size_t)(b * 8 + kc) * MLPDIM + tid];
        t1s[tid] = acc;
        __syncthreads();
        if (tid < NCLS) {
            float a2 = bd2[tid];
            for (int kx = 0; kx < MLPDIM; ++kx) a2 += t1s[kx] * Wd2[kx * NCLS + tid];
            out[b * NCLS + tid] = a2;
        }
        __syncthreads();
    }
}

// ---------------------------------------------------------------------------
// GAT: one 64-thread block per graph. Inner dims of hb/o1 padded 64->65 so
// reduction lanes (distinct n at fixed f) land on distinct banks (65 % 32 = 1).
// ---------------------------------------------------------------------------
__global__ __launch_bounds__(64) void gat_kernel(
    const float* __restrict__ x, const int* __restrict__ adj,
    const float* __restrict__ Wg, const float* __restrict__ ag,
    const float* __restrict__ Wgo, const float* __restrict__ ago,
    float* __restrict__ out)
{
    int g = blockIdx.x;
    int s = g / 5, jj = g % 5;
    int tid = threadIdx.x;
    __shared__ float xs[5][3];
    __shared__ int adjs[25];
    __shared__ float hb[GH][5][GHID + 1];
    __shared__ float o1[GH][5][GHID + 1];
    __shared__ float srcb[GH][5], dstb[GH][5];
    __shared__ float attb[GH][5][5];
    __shared__ float h2[5][5], src2[5], dst2[5], att2[5][5], o2[5][5];

    if (tid < 15) { int n = tid / 3, c = tid % 3;
        xs[n][c] = x[(size_t)n * SEQ * NTOK + (size_t)s * NTOK + jj * 3 + c]; }
    if (tid < 25) adjs[tid] = adj[tid];
    __syncthreads();

    #pragma unroll
    for (int hh = 0; hh < GH; ++hh)
        #pragma unroll
        for (int n = 0; n < 5; ++n)
            hb[hh][n][tid] = xs[n][0] * Wg[hh * 192 + tid]
                           + xs[n][1] * Wg[hh * 192 + 64 + tid]
                           + xs[n][2] * Wg[hh * 192 + 128 + tid];
    __syncthreads();

    if (tid < 15) { int hh = tid / 5, n = tid % 5; float a = 0.f;
        for (int f = 0; f < GHID; ++f) a += hb[hh][n][f] * ag[hh * 128 + f];
        srcb[hh][n] = a;
    } else if (tid >= 32 && tid < 47) { int t2 = tid - 32; int hh = t2 / 5, n = t2 % 5; float a = 0.f;
        for (int f = 0; f < GHID; ++f) a += hb[hh][n][f] * ag[hh * 128 + 64 + f];
        dstb[hh][n] = a;
    }
    __syncthreads();

    if (tid < 15) { int hh = tid / 5, i = tid % 5;
        float e[5]; float mx = -1e30f;
        #pragma unroll
        for (int j2 = 0; j2 < 5; ++j2) {
            float ev = srcb[hh][i] + dstb[hh][j2];
            ev = ev > 0.f ? ev : 0.2f * ev;
            e[j2] = ev;
            if (adjs[i * 5 + j2] && ev > mx) mx = ev;
        }
        float sum = 0.f;
        #pragma unroll
        for (int j2 = 0; j2 < 5; ++j2) {
            float p = adjs[i * 5 + j2] ? expf(e[j2] - mx) : 0.f;
            e[j2] = p; sum += p;
        }
        float inv = 1.f / sum;
        #pragma unroll
        for (int j2 = 0; j2 < 5; ++j2) attb[hh][i][j2] = e[j2] * inv;
    }
    __syncthreads();

    #pragma unroll
    for (int hh = 0; hh < GH; ++hh)
        #pragma unroll
        for (int n = 0; n < 5; ++n) {
            float a = 0.f;
            #pragma unroll
            for (int j2 = 0; j2 < 5; ++j2) a += attb[hh][n][j2] * hb[hh][j2][tid];
            o1[hh][n][tid] = a > 0.f ? a : expm1f(a);
        }
    __syncthreads();

    if (tid < 25) { int n = tid / 5, m = tid % 5; float a = 0.f;
        for (int hh = 0; hh < GH; ++hh)
            for (int f = 0; f < GHID; ++f)
                a += o1[hh][n][f] * Wgo[(hh * GHID + f) * GCLS + m];
        h2[n][m] = a;
    }
    __syncthreads();

    if (tid < 5) { float a = 0.f;
        for (int m = 0; m < GCLS; ++m) a += h2[tid][m] * ago[m];
        src2[tid] = a;
    } else if (tid >= 8 && tid < 13) { int n = tid - 8; float a = 0.f;
        for (int m = 0; m < GCLS; ++m) a += h2[n][m] * ago[GCLS + m];
        dst2[n] = a;
    }
    __syncthreads();

    if (tid < 5) { int i = tid;
        float e[5]; float mx = -1e30f;
        #pragma unroll
        for (int j2 = 0; j2 < 5; ++j2) {
            float ev = src2[i] + dst2[j2];
            ev = ev > 0.f ? ev : 0.2f * ev;
            e[j2] = ev;
            if (adjs[i * 5 + j2] && ev > mx) mx = ev;
        }
        float sum = 0.f;
        #pragma unroll
        for (int j2 = 0; j2 < 5; ++j2) {
            float p = adjs[i * 5 + j2] ? expf(e[j2] - mx) : 0.f;
            e[j2] = p; sum += p;
        }
        float inv = 1.f / sum;
        #pragma unroll
        for (int j2 = 0; j2 < 5; ++j2) att2[i][j2] = e[j2] * inv;
    }
    __syncthreads();

    if (tid < 25) { int n = tid / 5, m = tid % 5; float a = 0.f;
        #pragma unroll
        for (int j2 = 0; j2 < 5; ++j2) a += att2[n][j2] * h2[j2][m];
        o2[n][m] = a > 0.f ? a : expm1f(a);
    }
    __syncthreads();

    if (tid < 5) { int n = tid;
        float mx = o2[n][0];
        #pragma unroll
        for (int m = 1; m < GCLS; ++m) mx = fmaxf(mx, o2[n][m]);
        float sum = 0.f;
        #pragma unroll
        for (int m = 0; m < GCLS; ++m) sum += expf(o2[n][m] - mx);
        float ls = logf(sum);
        #pragma unroll
        for (int m = 0; m < GCLS; ++m)
            out[(size_t)g * 25 + n * 5 + m] = o2[n][m] - mx - ls;
    }
}

// ---------------------------------------------------------------------------
// Launch
// ---------------------------------------------------------------------------
extern "C" void kernel_launch(void* const* d_in, const int* in_sizes, int n_in,
                              void* d_out, int out_size, void* d_ws, size_t ws_size,
                              hipStream_t stream)
{
    const float* x       = (const float*)d_in[0];
    const int*   adj     = (const int*)  d_in[1];
    const float* W_enc   = (const float*)d_in[2];
    const float* b_enc   = (const float*)d_in[3];
    const float* cls_tok = (const float*)d_in[4];
    const float* pos_emb = (const float*)d_in[5];
    const float* Wq = (const float*)d_in[6];
    const float* bq = (const float*)d_in[7];
    const float* Wk = (const float*)d_in[8];
    const float* bk = (const float*)d_in[9];
    const float* Wv = (const float*)d_in[10];
    const float* bv = (const float*)d_in[11];
    const float* Wo = (const float*)d_in[12];
    const float* bo = (const float*)d_in[13];
    const float* W1 = (const float*)d_in[14];
    const float* b1 = (const float*)d_in[15];
    const float* W2 = (const float*)d_in[16];
    const float* b2 = (const float*)d_in[17];
    const float* g1 = (const float*)d_in[18];
    const float* be1= (const float*)d_in[19];
    const float* g2 = (const float*)d_in[20];
    const float* be2= (const float*)d_in[21];
    const float* Wd1= (const float*)d_in[22];
    const float* bd1= (const float*)d_in[23];
    const float* Wd2= (const float*)d_in[24];
    const float* bd2= (const float*)d_in[25];
    const float* Wg = (const float*)d_in[26];
    const float* ag = (const float*)d_in[27];
    const float* Wgo= (const float*)d_in[28];
    const float* ago= (const float*)d_in[29];
    float* out = (float*)d_out;

    // workspace layout (~91 MB)
    float* ws = (float*)d_ws;
    float* h = ws;
    unsigned short* hb   = (unsigned short*)(h + (size_t)MP * DM);
    unsigned short* qkvb = hb + (size_t)MP * DM;
    unsigned short* ob   = qkvb + (size_t)MP * QKVN;
    unsigned short* f1b  = qkvb;                    // alias qkvb+ob
    unsigned short* Wqkvt= ob + (size_t)MP * DM;
    unsigned short* Wot  = Wqkvt + (size_t)4 * QKVN * DM;
    unsigned short* W1t  = Wot + (size_t)4 * DM * DM;
    unsigned short* W2t  = W1t + (size_t)4 * DM * DFF;
    float* bqkv = (float*)(W2t + (size_t)4 * DFF * DM);
    float* dpart = bqkv + 4 * QKVN;
    unsigned short* vt = (unsigned short*)(dpart + NBATCH * 8 * MLPDIM);  // [40][64][TPAD]
    unsigned short* parts = vt + (size_t)40 * 64 * TPAD;   // [4][MP][512] bf16

    setup_kernel<<<12292, 256, 0, stream>>>(Wq, Wk, Wv, Wo, W1, W2, bq, bk, bv,
                                            Wqkvt, Wot, W1t, W2t, bqkv);

    gat_kernel<<<NGRAPH, 64, 0, stream>>>(x, adj, Wg, ag, Wgo, ago, out + NBATCH * NCLS);
    encoder_kernel<<<ROWS, 256, 0, stream>>>(x, W_enc, b_enc, cls_tok, pos_emb, h, hb);

    dim3 gqkv (QKVN / 128, MP / 128);        // (12, 41)
    dim3 g2048(DFF / 128, MP / 128);         // (16, 41)
    dim3 gWo  (DM / 128, MP / 128, 2);       // split-K=2
    dim3 gW2  (DM / 128, MP / 128, 4);       // split-K=4
    dim3 gAttn(17, NBATCH * NHEAD);          // 17 q-tiles x 40 bh
    dim3 gVt  (TPAD / 64, NBATCH * NHEAD);   // (18, 40)
    int gLN = (ROWS + 3) / 4;

    for (int i = 0; i < 4; ++i) {
        gemm_mfma<<<gqkv, 256, 0, stream>>>(hb, Wqkvt + (size_t)i*QKVN*DM, bqkv + i*QKVN, nullptr, qkvb, QKVN, DM, 0);
        vtrans_kernel<<<gVt, 256, 0, stream>>>(qkvb + 1024, vt, QKVN);
        attn_mfma<<<gAttn, 256, 0, stream>>>(qkvb, qkvb + 512, vt, ob, QKVN);
        gemm_mfma_sk<<<gWo, 256, 0, stream>>>(ob, Wot + (size_t)i*DM*DM, parts, DM, DM);
        add_lnp_kernel<<<gLN, 256, 0, stream>>>(h, parts, 2, bo + i*DM, g1 + i*DM, be1 + i*DM, hb);
        gemm_mfma<<<g2048, 256, 0, stream>>>(hb,  W1t + (size_t)i*DM*DFF, b1 + i*DFF, nullptr, f1b, DFF, DM, 1);
        gemm_mfma_sk<<<gW2, 256, 0, stream>>>(f1b, W2t + (size_t)i*DM*DFF, parts, DM, DFF);
        add_lnp_kernel<<<gLN, 256, 0, stream>>>(h, parts, 4, b2 + i*DM, g2 + i*DM, be2 + i*DM, hb);
    }

    dec1_kernel<<<dim3(8, NBATCH), 256, 0, stream>>>(h, Wd1, dpart);
    dec2_kernel<<<1, 256, 0, stream>>>(dpart, bd1, Wd2, bd2, out);
}